// Round 15
// baseline (7214.337 us; speedup 1.0000x reference)
//
#include <hip/hip_runtime.h>
#include <cstdint>

#define DEV __device__ __forceinline__

typedef unsigned short ushort8 __attribute__((ext_vector_type(8)));
typedef unsigned int uint32;

#if __has_builtin(__builtin_amdgcn_rcpf)
DEV float rcp_fast(float x) { return __builtin_amdgcn_rcpf(x); }
#else
DEV float rcp_fast(float x) { return 1.f / x; }
#endif
#if __has_builtin(__builtin_amdgcn_exp2f)
DEV float exp2_fast(float x) { return __builtin_amdgcn_exp2f(x); }
#else
DEV float exp2_fast(float x) { return exp2f(x); }
#endif

#define SCALE2LOG2E 2.8853900817779268f  // 2*log2(e)
#define LOG2E 1.4426950408889634f

// tanh(x) = 1 - 2/(2^(x*SCALE2LOG2E)+1): safe at +/-inf.
DEV float tanh_fast(float x) {
  float z = exp2_fast(x * SCALE2LOG2E);
  return 1.f - 2.f * rcp_fast(z + 1.f);
}
DEV float sigmoid_fast(float x) {
  return rcp_fast(1.f + exp2_fast(-LOG2E * x));
}

// bf16 helpers (RTN pack; unpack via bit shift).
DEV unsigned short f2bf(float f) {
  uint32 u = __float_as_uint(f);
  u += 0x7FFFu + ((u >> 16) & 1u);
  return (unsigned short)(u >> 16);
}
DEV float bf2f(unsigned short s) { return __uint_as_float(((uint32)s) << 16); }
DEV float bf2f_lo(uint32 u) { return __uint_as_float(u << 16); }
DEV float bf2f_hi(uint32 u) { return __uint_as_float(u & 0xFFFF0000u); }

// ------- prep: decoder cell weights -> bf16 n-pair-packed dwords -----------
// out[g][l][n2][m] = pack(w[l][2*n2][m], w[l][2*n2+1][m]); g=0:RHw, g=1:RTw.
__global__ __launch_bounds__(256) void k_prep(const float* __restrict__ RHw,
                                              const float* __restrict__ RTw,
                                              uint32* __restrict__ out) {
  int i = blockIdx.x * 256 + threadIdx.x;
  if (i >= 49152) return;
  int g = i / 24576, rem = i % 24576;
  int l = rem / 8192, n2 = (rem >> 7) & 63, m = rem & 127;
  const float* W = g ? RTw : RHw;
  float w0 = W[(size_t)(l * 128 + 2 * n2) * 128 + m];
  float w1 = W[(size_t)(l * 128 + 2 * n2 + 1) * 128 + m];
  out[i] = (uint32)f2bf(w0) | ((uint32)f2bf(w1) << 16);
}

// ---------------- conv0: [B,T,16] -> [B,T,64], k=5 pad=2, +bias, ReLU ------
__global__ __launch_bounds__(256) void k_conv0(
    const float* __restrict__ x, const float* __restrict__ w,
    const float* __restrict__ bias, float* __restrict__ out) {
  __shared__ float wl[16 * 5 * 64];
  __shared__ float xl[68 * 16];
  const int blk = blockIdx.x;
  const int b = blk >> 2, tt = blk & 3;
  const int tid = threadIdx.x;
  for (int i = tid; i < 5120; i += 256) {
    int o = i / 80, rem = i % 80, ii = rem / 5, kk = rem % 5;
    wl[(ii * 5 + kk) * 64 + o] = w[i];
  }
  const int t0 = tt * 64;
  for (int i = tid; i < 68 * 16; i += 256) {
    int row = i >> 4, c = i & 15;
    int t = t0 - 2 + row;
    xl[i] = (t >= 0 && t < 256) ? x[((b << 8) + t) * 16 + c] : 0.f;
  }
  __syncthreads();
  const int o = tid & 63, tr = tid >> 6;
  for (int j = 0; j < 16; ++j) {
    int tl = tr * 16 + j;
    float acc = bias[o];
#pragma unroll
    for (int kk = 0; kk < 5; ++kk)
#pragma unroll
      for (int ii = 0; ii < 16; ++ii)
        acc += xl[(tl + kk) * 16 + ii] * wl[(ii * 5 + kk) * 64 + o];
    out[((b << 8) + t0 + tl) * 64 + o] = fmaxf(acc, 0.f);
  }
}

// ------ conv1: [B,T,64] -> [B,T,64], k=5 pad=2, +bias, ReLU (o-split) ------
__global__ __launch_bounds__(256) void k_conv1(
    const float* __restrict__ in0, const float* __restrict__ w,
    const float* __restrict__ bias, float* __restrict__ out) {
  __shared__ float wl[64 * 5 * 32];  // 40 KB
  __shared__ float xl[68 * 64];      // 17 KB
  const int blk = blockIdx.x;
  const int b = blk >> 3, rem0 = blk & 7, tt = rem0 >> 1, oh = rem0 & 1;
  const int tid = threadIdx.x;
  for (int i = tid; i < 10240; i += 256) {
    int op = i / 320, r2 = i % 320, ii = r2 / 5, kk = r2 % 5;
    wl[(ii * 5 + kk) * 32 + op] = w[(size_t)(oh * 32 + op) * 320 + r2];
  }
  const int t0 = tt * 64;
  for (int i = tid; i < 68 * 64; i += 256) {
    int row = i >> 6, c = i & 63;
    int t = t0 - 2 + row;
    xl[i] = (t >= 0 && t < 256) ? in0[((b << 8) + t) * 64 + c] : 0.f;
  }
  __syncthreads();
  const int op = tid & 31, tr = tid >> 5;
  for (int j = 0; j < 8; ++j) {
    int tl = tr * 8 + j;
    float acc = bias[oh * 32 + op];
    for (int kk = 0; kk < 5; ++kk) {
#pragma unroll 16
      for (int ii = 0; ii < 64; ++ii)
        acc += xl[(tl + kk) * 64 + ii] * wl[(ii * 5 + kk) * 32 + op];
    }
    out[((b << 8) + t0 + tl) * 64 + oh * 32 + op] = fmaxf(acc, 0.f);
  }
}

// --------- c2e (+bias) fused with encoder input projections x@WH, x@WT -----
__global__ __launch_bounds__(256) void k_c2e_proj(
    const float* __restrict__ in1, const float* __restrict__ cw,
    const float* __restrict__ cb, const float* __restrict__ WH,
    const float* __restrict__ WT, float* __restrict__ xph,
    float* __restrict__ xpt) {
  __shared__ float xin[64 * 64];
  __shared__ float w1[64 * 64];
  __shared__ float xe[64 * 64];
  __shared__ float wh[64 * 128];
  __shared__ float wt[64 * 128];
  const int blk = blockIdx.x;
  const int b = blk >> 2, tt = blk & 3;
  const int tid = threadIdx.x;
  for (int i = tid; i < 4096; i += 256) {
    xin[i] = in1[(size_t)(((b << 8) + tt * 64)) * 64 + i];
    w1[i] = cw[i];
  }
  for (int i = tid; i < 8192; i += 256) {
    wh[i] = WH[i];
    wt[i] = WT[i];
  }
  __syncthreads();
  {
    const int o = tid & 63, tr = tid >> 6;
    for (int j = 0; j < 16; ++j) {
      int tl = tr * 16 + j;
      float acc = cb[o];
#pragma unroll 16
      for (int k = 0; k < 64; ++k) acc += xin[tl * 64 + k] * w1[k * 64 + o];
      xe[tl * 64 + o] = acc;
    }
  }
  __syncthreads();
  {
    const int m = tid & 127, hf = tid >> 7;
    for (int j = 0; j < 32; ++j) {
      int tl = hf * 32 + j;
      float a0 = 0.f, a1 = 0.f;
#pragma unroll 16
      for (int k = 0; k < 64; ++k) {
        float xv = xe[tl * 64 + k];
        a0 += xv * wh[k * 128 + m];
        a1 += xv * wt[k * 128 + m];
      }
      size_t oidx = (size_t)((b << 8) + tt * 64 + tl) * 128 + m;
      xph[oidx] = a0;
      xpt[oidx] = a1;
    }
  }
}

// ---------------- encoder RHN: one block per batch row ---------------------
__global__ __launch_bounds__(512, 2) void k_encoder(
    const float* __restrict__ xph, const float* __restrict__ xpt,
    const float* __restrict__ RHw, const float* __restrict__ RHb,
    const float* __restrict__ RTw, const float* __restrict__ RTb,
    unsigned short* __restrict__ h_bf) {
  const int b = blockIdx.x;
  const int tid = threadIdx.x;
  const int g = tid >> 8;
  const int m = (tid >> 1) & 127;
  const int hf = tid & 1;
  const float* W = g ? RTw : RHw;
  const float* Bb = g ? RTb : RHb;
  const float* XP = g ? xpt : xph;
  float wreg[3][64];
#pragma unroll
  for (int l = 0; l < 3; ++l)
#pragma unroll
    for (int j = 0; j < 64; ++j)
      wreg[l][j] = W[(size_t)(l * 128 + hf * 64 + j) * 128 + m];
  float bias[3];
#pragma unroll
  for (int l = 0; l < 3; ++l) bias[l] = Bb[l * 128 + m];

  __shared__ float s_lds[128];
  __shared__ float hg[128];
  __shared__ float tg[128];
  if (tid < 128) s_lds[tid] = 0.f;
  __syncthreads();

  for (int t = 0; t < 256; ++t) {
    const float xp = XP[(size_t)((b << 8) + t) * 128 + m];
#pragma unroll
    for (int l = 0; l < 3; ++l) {
      float acc = (hf == 0) ? (bias[l] + (l == 0 ? xp : 0.f)) : 0.f;
      const float* sp = s_lds + hf * 64;
#pragma unroll
      for (int j = 0; j < 64; ++j) acc += sp[j] * wreg[l][j];
      float tot = acc + __shfl_xor(acc, 1);
      if (hf == 0) {
        if (g == 0) hg[m] = tanh_fast(tot);
        else        tg[m] = sigmoid_fast(tot);
      }
      __syncthreads();
      if (tid < 128) {
        float tv = tg[tid];
        float sn = hg[tid] * tv + (1.f - tv) * s_lds[tid];
        s_lds[tid] = sn;
        h_bf[((size_t)(b * 3 + l) * 256 + t) * 128 + tid] = f2bf(sn);
      }
      __syncthreads();
    }
  }
}

// Uh2 = bf16(SCALE2LOG2E*(h.Uk_w[r]+Uk_b[r])) fused with hv = h.Vt_w[r],
// hv2 = h.V_w[r] (reuses the staged hl tile; 8-lane shuffle reduce per row).
__global__ __launch_bounds__(256, 2) void k_uh(
    const unsigned short* __restrict__ h_bf, const float* __restrict__ Uk_w,
    const float* __restrict__ Uk_b, const float* __restrict__ Vt_w,
    const float* __restrict__ V_w, unsigned short* __restrict__ Uh_bf,
    float* __restrict__ hv, float* __restrict__ hv2) {
  __shared__ float wl[128 * 128];  // 64 KB
  __shared__ float hl[32 * 128];   // 16 KB
  __shared__ float vtl[128], vwl[128];
  const int blk = blockIdx.x;      // 768 = 256 b x 3 r
  const int b = blk / 3, r = blk % 3;
  const int tid = threadIdx.x;
  for (int i = tid; i < 16384; i += 256) wl[i] = Uk_w[(size_t)r * 16384 + i];
  if (tid < 128) {
    vtl[tid] = Vt_w[r * 128 + tid];
    vwl[tid] = V_w[r * 128 + tid];
  }
  const int m = tid & 127, tr = tid >> 7;
  const float ub = Uk_b[r * 128 + m];
  const int hrow = tid >> 3, hc = tid & 7;
  for (int tt = 0; tt < 8; ++tt) {
    const size_t hbase = ((size_t)(b * 3 + r) * 256 + tt * 32) * 128;
    __syncthreads();
    const ushort8* hvv = (const ushort8*)(h_bf + hbase);
    for (int i = tid; i < 512; i += 256) {
      ushort8 u = hvv[i];
#pragma unroll
      for (int j = 0; j < 8; ++j) hl[i * 8 + j] = bf2f(u[j]);
    }
    __syncthreads();
    {
      float a1 = 0.f, a2 = 0.f;
      const float* hp = hl + hrow * 128 + hc * 16;
      const float* vt = vtl + hc * 16;
      const float* vw = vwl + hc * 16;
#pragma unroll
      for (int k = 0; k < 16; ++k) {
        float h = hp[k];
        a1 += h * vt[k];
        a2 += h * vw[k];
      }
      a1 += __shfl_xor(a1, 1); a1 += __shfl_xor(a1, 2); a1 += __shfl_xor(a1, 4);
      a2 += __shfl_xor(a2, 1); a2 += __shfl_xor(a2, 2); a2 += __shfl_xor(a2, 4);
      if (hc == 0) {
        size_t o = (size_t)(b * 3 + r) * 256 + tt * 32 + hrow;
        hv[o] = a1;
        hv2[o] = a2;
      }
    }
    for (int j = 0; j < 16; ++j) {
      int tl = tr * 16 + j;
      float acc = ub;
#pragma unroll 16
      for (int n = 0; n < 128; ++n) acc += hl[tl * 128 + n] * wl[n * 128 + m];
      Uh_bf[hbase + (size_t)tl * 128 + m] = f2bf(acc * SCALE2LOG2E);
    }
  }
}

// ---------------- attentive RHN decoder: one block per batch row -----------
// r13 base with phases 2+3 MERGED: after the two intra-quad shuffles every
// lane holds the full e[r]; quad-slot q4 takes r=q4 (select chain, NOT a
// dynamic index), computes p=exp(e) and reduces num/den over the wave's 16
// t-values via a segregated butterfly (xor 4..32). Removes 1 barrier, the
// a_lds round-trip, and the standalone p-phase. 8 barriers/step.
__global__ __launch_bounds__(1024, 4) void k_decoder(
    const float* __restrict__ y, const unsigned short* __restrict__ Uh_bf,
    const float* __restrict__ hv_g, const float* __restrict__ hv2_g,
    const float* __restrict__ Tk_w, const float* __restrict__ vk_w,
    const float* __restrict__ vk_b, const float* __restrict__ Wt_w,
    const float* __restrict__ Vt_b, const float* __restrict__ WHd,
    const float* __restrict__ WTd, const uint32* __restrict__ cellw,
    const float* __restrict__ RHb, const float* __restrict__ RTb,
    const float* __restrict__ W_w, const float* __restrict__ W_b,
    const float* __restrict__ V_b, float* __restrict__ out) {
  const int b = blockIdx.x, tid = threadIdx.x;

  __shared__ uint32 tk_lds[24576];  // 96 KiB packed prescaled bf16 n-pairs
  __shared__ __align__(8) float Ts_lds[3 * 136];  // padded 34-float windows
  __shared__ __align__(8) float vk_pad[3 * 136];  // -2*vk, same layout
  __shared__ float hv_lds[768], hv2_lds[768];
  __shared__ __align__(8) float s_lds[128];
  __shared__ float cpart[8 * 128];
  __shared__ float bias_lds[1024];  // RHb[384] RTb[384] WHd[128] WTd[128]
  __shared__ float y_lds[256];
  __shared__ float redN[48], redD[48], redN2[48];  // [wave][r]
  __shared__ float svk_lds[3];
  __shared__ float ytil_lds;

  // ---- one-time LDS fills ----
  for (int i = tid; i < 24576; i += 1024) {
    int r = i >> 13, rem = i & 8191, j = rem >> 7, m = rem & 127;
    float g0 = Tk_w[(size_t)r * 16384 + (2 * j) * 128 + m] * SCALE2LOG2E;
    float g1 = Tk_w[(size_t)r * 16384 + (2 * j + 1) * 128 + m] * SCALE2LOG2E;
    tk_lds[r * 8192 + m * 64 + (j ^ (m & 31))] =
        (uint32)f2bf(g0) | ((uint32)f2bf(g1) << 16);
  }
  if (tid < 384) {
    int r = tid >> 7, m = tid & 127;
    vk_pad[r * 136 + (m >> 5) * 34 + (m & 31)] = -2.f * vk_w[tid];
    bias_lds[tid] = RHb[tid];
    bias_lds[384 + tid] = RTb[tid];
  }
  if (tid < 3) {
    float sv = vk_b[tid];
    for (int m = 0; m < 128; ++m) sv += vk_w[tid * 128 + m];
    svk_lds[tid] = sv;
  }
  if (tid < 128) {
    bias_lds[768 + tid] = WHd[tid];
    bias_lds[896 + tid] = WTd[tid];
    s_lds[tid] = 0.f;
  }
  if (tid < 256) y_lds[tid] = y[(b << 8) + tid];
  if (tid < 768) {
    hv_lds[tid] = hv_g[(size_t)b * 768 + tid];
    hv2_lds[tid] = hv2_g[(size_t)b * 768 + tid];
  }
  const float wt0 = Wt_w[0], vtb0 = Vt_b[0];

  // ---- persistent prescaled Uh: 3 r x 16 dwords = 48 VGPR ----
  const int t_e4 = tid >> 2, q4 = tid & 3;
  uint32 ureg[3][16];
#pragma unroll
  for (int r = 0; r < 3; ++r) {
    const uint4* up = (const uint4*)(Uh_bf +
        ((size_t)(b * 3 + r) * 256 + t_e4) * 128 + q4 * 32);
#pragma unroll
    for (int q = 0; q < 4; ++q) {
      uint4 v = up[q];
      ureg[r][4 * q + 0] = v.x;
      ureg[r][4 * q + 1] = v.y;
      ureg[r][4 * q + 2] = v.z;
      ureg[r][4 * q + 3] = v.w;
    }
  }
  uint32 zr;
  asm volatile("s_mov_b32 %0, 0" : "=s"(zr));
#pragma unroll
  for (int r = 0; r < 3; ++r)
#pragma unroll
    for (int q = 0; q < 16; ++q) ureg[r][q] ^= zr;
  __syncthreads();

  const int lane = tid & 63, wv = tid >> 6;
  // Ts-phase roles (tid < 768)
  const int r3t = (tid >> 8) & 3, m2 = (tid >> 1) & 127, p2 = tid & 1;
  // cell roles: 2 gates x 4 n2-chunks x 128 m
  const int gc = tid >> 9, ch = (tid >> 7) & 3, mc = tid & 127;
  const uint32* Wc = cellw + gc * 24576 + mc;
  const int n2base = ch * 16;

  for (int step = 0; step < 256; ++step) {
    // ---- (1) Ts2[r][m] = s @ Tk2[r] ----
    if (tid < 768) {
      const uint32* tkp = tk_lds + r3t * 8192 + m2 * 64;
      const int swz = m2 & 31;
      const float* sp = s_lds + p2 * 64;
      const int jb = p2 * 32;
      float acc = 0.f;
#pragma unroll 8
      for (int jj = 0; jj < 32; ++jj) {
        uint32 w = tkp[(jb + jj) ^ swz];
        float2 sv = *(const float2*)(sp + 2 * jj);
        acc += sv.x * bf2f_lo(w) + sv.y * bf2f_hi(w);
      }
      float tot = acc + __shfl_xor(acc, 1);
      if (p2 == 0) Ts_lds[r3t * 136 + (m2 >> 5) * 34 + (m2 & 31)] = tot;
    }
    __syncthreads();  // (1)
    // ---- (2) e + p + segregated num/den reduce (a_lds phase eliminated) ----
    {
      float er[3];
#pragma unroll
      for (int r = 0; r < 3; ++r) {
        const float2* ts2 = (const float2*)(Ts_lds + r * 136 + q4 * 34);
        const float2* vk2 = (const float2*)(vk_pad + r * 136 + q4 * 34);
        float acc0 = 0.f, acc1 = 0.f;
#pragma unroll
        for (int j = 0; j < 16; ++j) {
          uint32 w = ureg[r][j];
          float2 t2 = ts2[j], v2 = vk2[j];
          float z0 = exp2_fast(bf2f_lo(w) + t2.x);
          float z1 = exp2_fast(bf2f_hi(w) + t2.y);
          acc0 += v2.x * rcp_fast(z0 + 1.f);
          acc1 += v2.y * rcp_fast(z1 + 1.f);
        }
        float a = acc0 + acc1;
        a += __shfl_xor(a, 1);
        a += __shfl_xor(a, 2);
        er[r] = a;
      }
      // quad-slot q4 owns r=q4 (select chain, no dynamic indexing; q4==3 idles)
      float ev = er[0] + svk_lds[0];
      if (q4 == 1) ev = er[1] + svk_lds[1];
      if (q4 == 2) ev = er[2] + svk_lds[2];
      float pn = 0.f, pd = 0.f, pn2 = 0.f;
      if (q4 < 3) {
        float p = __expf(ev);
        pd = p;
        pn = p * hv_lds[q4 * 256 + t_e4];
        if (step == 255) pn2 = p * hv2_lds[q4 * 256 + t_e4];
      }
#pragma unroll
      for (int off = 4; off < 64; off <<= 1) {  // keeps q4 classes separate
        pn += __shfl_xor(pn, off);
        pd += __shfl_xor(pd, off);
      }
      if (step == 255) {
#pragma unroll
        for (int off = 4; off < 64; off <<= 1) pn2 += __shfl_xor(pn2, off);
        if (lane < 3) redN2[wv * 3 + lane] = pn2;
      }
      if (lane < 3) {
        redN[wv * 3 + lane] = pn;
        redD[wv * 3 + lane] = pd;
      }
    }
    __syncthreads();  // (2)
    // ---- cell: 3 micro-steps; l=0 dot overlaps ytil scalar ----
    const float2* sp2 = (const float2*)s_lds;
#pragma unroll
    for (int l = 0; l < 3; ++l) {
      {
        float acc = 0.f;
        const uint32* wp = Wc + (size_t)(l * 64 + n2base) * 128;
#pragma unroll 8
        for (int n2 = 0; n2 < 16; ++n2) {
          uint32 w = wp[(size_t)n2 * 128];
          float2 sv = sp2[n2base + n2];
          acc += sv.x * bf2f_lo(w) + sv.y * bf2f_hi(w);
        }
        cpart[(gc * 4 + ch) * 128 + mc] = acc;
        if (l == 0 && tid == 0) {
          float yt = y_lds[step] * wt0 + vtb0;
#pragma unroll
          for (int r = 0; r < 3; ++r) {
            float ns = 0.f, ds = 0.f;
#pragma unroll
            for (int w = 0; w < 16; ++w) {
              ns += redN[w * 3 + r];
              ds += redD[w * 3 + r];
            }
            yt += ns * rcp_fast(ds);
          }
          ytil_lds = yt;
        }
      }
      __syncthreads();  // cell A
      if (tid < 128) {
        float ha = cpart[tid] + cpart[128 + tid] + cpart[256 + tid] +
                   cpart[384 + tid] + bias_lds[l * 128 + tid];
        float ta = cpart[512 + tid] + cpart[640 + tid] + cpart[768 + tid] +
                   cpart[896 + tid] + bias_lds[384 + l * 128 + tid];
        if (l == 0) {
          float yt = ytil_lds;
          ha += yt * bias_lds[768 + tid];
          ta += yt * bias_lds[896 + tid];
        }
        float hvv = tanh_fast(ha);
        float tv = sigmoid_fast(ta);
        s_lds[tid] = hvv * tv + (1.f - tv) * s_lds[tid];
      }
      __syncthreads();  // cell B
    }
  }
  // ---- output head: out[b] = s.W_w + W_b + V_b + sum_r num2[r]/den[r] ----
  if (tid < 64) {
    float acc = s_lds[tid] * W_w[tid] + s_lds[tid + 64] * W_w[tid + 64];
#pragma unroll
    for (int off = 32; off; off >>= 1) acc += __shfl_xor(acc, off);
    if (tid == 0) {
      float o = acc + W_b[0] + V_b[0];
#pragma unroll
      for (int r = 0; r < 3; ++r) {
        float ns = 0.f, ds = 0.f;
#pragma unroll
        for (int w = 0; w < 16; ++w) {
          ns += redN2[w * 3 + r];
          ds += redD[w * 3 + r];
        }
        o += ns * rcp_fast(ds);
      }
      out[b] = o;
    }
  }
}

extern "C" void kernel_launch(void* const* d_in, const int* in_sizes, int n_in,
                              void* d_out, int out_size, void* d_ws,
                              size_t ws_size, hipStream_t stream) {
  (void)in_sizes; (void)n_in; (void)out_size; (void)ws_size;
  const float* x    = (const float*)d_in[0];
  const float* y    = (const float*)d_in[1];
  const float* c0w  = (const float*)d_in[2];
  const float* c0b  = (const float*)d_in[3];
  const float* c1w  = (const float*)d_in[4];
  const float* c1b  = (const float*)d_in[5];
  const float* c2ew = (const float*)d_in[6];
  const float* c2eb = (const float*)d_in[7];
  const float* eWH  = (const float*)d_in[8];
  const float* eWT  = (const float*)d_in[9];
  const float* eRHw = (const float*)d_in[10];
  const float* eRHb = (const float*)d_in[11];
  const float* eRTw = (const float*)d_in[12];
  const float* eRTb = (const float*)d_in[13];
  const float* dWH  = (const float*)d_in[14];
  const float* dWT  = (const float*)d_in[15];
  const float* dRHw = (const float*)d_in[16];
  const float* dRHb = (const float*)d_in[17];
  const float* dRTw = (const float*)d_in[18];
  const float* dRTb = (const float*)d_in[19];
  const float* Tk   = (const float*)d_in[20];
  const float* Ukw  = (const float*)d_in[21];
  const float* Ukb  = (const float*)d_in[22];
  const float* vkw  = (const float*)d_in[23];
  const float* vkb  = (const float*)d_in[24];
  const float* Wtw  = (const float*)d_in[25];
  const float* Vtw  = (const float*)d_in[26];
  const float* Vtb  = (const float*)d_in[27];
  const float* Ww   = (const float*)d_in[28];
  const float* Wb   = (const float*)d_in[29];
  const float* Vw   = (const float*)d_in[30];
  const float* Vb   = (const float*)d_in[31];
  float* out = (float*)d_out;
  float* ws = (float*)d_ws;

  // Workspace layout (float units), same as round 5.
  unsigned short* h_bf  = (unsigned short*)ws;
  unsigned short* Uh_bf = (unsigned short*)(ws + 12582912);
  float* xph = ws + 12582912;
  float* xpt = ws + 20971520;
  float* c0o = ws + 29360128;
  float* hv  = ws + 29360128;   // aliases c0o (dead by k_uh time)
  float* hv2 = ws + 30146560;
  float* c1o = ws + 33554432;
  uint32* cellw = (uint32*)(ws + 37748736);

  k_prep<<<192, 256, 0, stream>>>(dRHw, dRTw, cellw);
  k_conv0<<<1024, 256, 0, stream>>>(x, c0w, c0b, c0o);
  k_conv1<<<2048, 256, 0, stream>>>(c0o, c1w, c1b, c1o);
  k_c2e_proj<<<1024, 256, 0, stream>>>(c1o, c2ew, c2eb, eWH, eWT, xph, xpt);
  k_encoder<<<256, 512, 0, stream>>>(xph, xpt, eRHw, eRHb, eRTw, eRTb, h_bf);
  k_uh<<<768, 256, 0, stream>>>(h_bf, Ukw, Ukb, Vtw, Vw, Uh_bf, hv, hv2);
  k_decoder<<<256, 1024, 0, stream>>>(y, Uh_bf, hv, hv2, Tk, vkw, vkb, Wtw,
                                      Vtb, dWH, dWT, cellw, dRHb, dRTb,
                                      Ww, Wb, Vb, out);
}

// Round 16
// 4933.488 us; speedup vs baseline: 1.4623x; 1.4623x over previous
//
#include <hip/hip_runtime.h>
#include <cstdint>

#define DEV __device__ __forceinline__

typedef unsigned short ushort8 __attribute__((ext_vector_type(8)));
typedef unsigned int uint32;

#if __has_builtin(__builtin_amdgcn_rcpf)
DEV float rcp_fast(float x) { return __builtin_amdgcn_rcpf(x); }
#else
DEV float rcp_fast(float x) { return 1.f / x; }
#endif
#if __has_builtin(__builtin_amdgcn_exp2f)
DEV float exp2_fast(float x) { return __builtin_amdgcn_exp2f(x); }
#else
DEV float exp2_fast(float x) { return exp2f(x); }
#endif

#define SCALE2LOG2E 2.8853900817779268f  // 2*log2(e)
#define LOG2E 1.4426950408889634f

// tanh(x) = 1 - 2/(2^(x*SCALE2LOG2E)+1): safe at +/-inf.
DEV float tanh_fast(float x) {
  float z = exp2_fast(x * SCALE2LOG2E);
  return 1.f - 2.f * rcp_fast(z + 1.f);
}
DEV float sigmoid_fast(float x) {
  return rcp_fast(1.f + exp2_fast(-LOG2E * x));
}

// bf16 helpers (RTN pack; unpack via bit shift).
DEV unsigned short f2bf(float f) {
  uint32 u = __float_as_uint(f);
  u += 0x7FFFu + ((u >> 16) & 1u);
  return (unsigned short)(u >> 16);
}
DEV float bf2f(unsigned short s) { return __uint_as_float(((uint32)s) << 16); }
DEV float bf2f_lo(uint32 u) { return __uint_as_float(u << 16); }
DEV float bf2f_hi(uint32 u) { return __uint_as_float(u & 0xFFFF0000u); }

// ------- prep: decoder cell weights -> bf16 n-pair-packed dwords -----------
// out[g][l][n2][m] = pack(w[l][2*n2][m], w[l][2*n2+1][m]); g=0:RHw, g=1:RTw.
__global__ __launch_bounds__(256) void k_prep(const float* __restrict__ RHw,
                                              const float* __restrict__ RTw,
                                              uint32* __restrict__ out) {
  int i = blockIdx.x * 256 + threadIdx.x;
  if (i >= 49152) return;
  int g = i / 24576, rem = i % 24576;
  int l = rem / 8192, n2 = (rem >> 7) & 63, m = rem & 127;
  const float* W = g ? RTw : RHw;
  float w0 = W[(size_t)(l * 128 + 2 * n2) * 128 + m];
  float w1 = W[(size_t)(l * 128 + 2 * n2 + 1) * 128 + m];
  out[i] = (uint32)f2bf(w0) | ((uint32)f2bf(w1) << 16);
}

// ---------------- conv0: [B,T,16] -> [B,T,64], k=5 pad=2, +bias, ReLU ------
__global__ __launch_bounds__(256) void k_conv0(
    const float* __restrict__ x, const float* __restrict__ w,
    const float* __restrict__ bias, float* __restrict__ out) {
  __shared__ float wl[16 * 5 * 64];
  __shared__ float xl[68 * 16];
  const int blk = blockIdx.x;
  const int b = blk >> 2, tt = blk & 3;
  const int tid = threadIdx.x;
  for (int i = tid; i < 5120; i += 256) {
    int o = i / 80, rem = i % 80, ii = rem / 5, kk = rem % 5;
    wl[(ii * 5 + kk) * 64 + o] = w[i];
  }
  const int t0 = tt * 64;
  for (int i = tid; i < 68 * 16; i += 256) {
    int row = i >> 4, c = i & 15;
    int t = t0 - 2 + row;
    xl[i] = (t >= 0 && t < 256) ? x[((b << 8) + t) * 16 + c] : 0.f;
  }
  __syncthreads();
  const int o = tid & 63, tr = tid >> 6;
  for (int j = 0; j < 16; ++j) {
    int tl = tr * 16 + j;
    float acc = bias[o];
#pragma unroll
    for (int kk = 0; kk < 5; ++kk)
#pragma unroll
      for (int ii = 0; ii < 16; ++ii)
        acc += xl[(tl + kk) * 16 + ii] * wl[(ii * 5 + kk) * 64 + o];
    out[((b << 8) + t0 + tl) * 64 + o] = fmaxf(acc, 0.f);
  }
}

// ------ conv1: [B,T,64] -> [B,T,64], k=5 pad=2, +bias, ReLU (o-split) ------
__global__ __launch_bounds__(256) void k_conv1(
    const float* __restrict__ in0, const float* __restrict__ w,
    const float* __restrict__ bias, float* __restrict__ out) {
  __shared__ float wl[64 * 5 * 32];  // 40 KB
  __shared__ float xl[68 * 64];      // 17 KB
  const int blk = blockIdx.x;
  const int b = blk >> 3, rem0 = blk & 7, tt = rem0 >> 1, oh = rem0 & 1;
  const int tid = threadIdx.x;
  for (int i = tid; i < 10240; i += 256) {
    int op = i / 320, r2 = i % 320, ii = r2 / 5, kk = r2 % 5;
    wl[(ii * 5 + kk) * 32 + op] = w[(size_t)(oh * 32 + op) * 320 + r2];
  }
  const int t0 = tt * 64;
  for (int i = tid; i < 68 * 64; i += 256) {
    int row = i >> 6, c = i & 63;
    int t = t0 - 2 + row;
    xl[i] = (t >= 0 && t < 256) ? in0[((b << 8) + t) * 64 + c] : 0.f;
  }
  __syncthreads();
  const int op = tid & 31, tr = tid >> 5;
  for (int j = 0; j < 8; ++j) {
    int tl = tr * 8 + j;
    float acc = bias[oh * 32 + op];
    for (int kk = 0; kk < 5; ++kk) {
#pragma unroll 16
      for (int ii = 0; ii < 64; ++ii)
        acc += xl[(tl + kk) * 64 + ii] * wl[(ii * 5 + kk) * 32 + op];
    }
    out[((b << 8) + t0 + tl) * 64 + oh * 32 + op] = fmaxf(acc, 0.f);
  }
}

// --------- c2e (+bias) fused with encoder input projections x@WH, x@WT -----
__global__ __launch_bounds__(256) void k_c2e_proj(
    const float* __restrict__ in1, const float* __restrict__ cw,
    const float* __restrict__ cb, const float* __restrict__ WH,
    const float* __restrict__ WT, float* __restrict__ xph,
    float* __restrict__ xpt) {
  __shared__ float xin[64 * 64];
  __shared__ float w1[64 * 64];
  __shared__ float xe[64 * 64];
  __shared__ float wh[64 * 128];
  __shared__ float wt[64 * 128];
  const int blk = blockIdx.x;
  const int b = blk >> 2, tt = blk & 3;
  const int tid = threadIdx.x;
  for (int i = tid; i < 4096; i += 256) {
    xin[i] = in1[(size_t)(((b << 8) + tt * 64)) * 64 + i];
    w1[i] = cw[i];
  }
  for (int i = tid; i < 8192; i += 256) {
    wh[i] = WH[i];
    wt[i] = WT[i];
  }
  __syncthreads();
  {
    const int o = tid & 63, tr = tid >> 6;
    for (int j = 0; j < 16; ++j) {
      int tl = tr * 16 + j;
      float acc = cb[o];
#pragma unroll 16
      for (int k = 0; k < 64; ++k) acc += xin[tl * 64 + k] * w1[k * 64 + o];
      xe[tl * 64 + o] = acc;
    }
  }
  __syncthreads();
  {
    const int m = tid & 127, hf = tid >> 7;
    for (int j = 0; j < 32; ++j) {
      int tl = hf * 32 + j;
      float a0 = 0.f, a1 = 0.f;
#pragma unroll 16
      for (int k = 0; k < 64; ++k) {
        float xv = xe[tl * 64 + k];
        a0 += xv * wh[k * 128 + m];
        a1 += xv * wt[k * 128 + m];
      }
      size_t oidx = (size_t)((b << 8) + tt * 64 + tl) * 128 + m;
      xph[oidx] = a0;
      xpt[oidx] = a1;
    }
  }
}

// ---------------- encoder RHN: one block per batch row ---------------------
__global__ __launch_bounds__(512, 2) void k_encoder(
    const float* __restrict__ xph, const float* __restrict__ xpt,
    const float* __restrict__ RHw, const float* __restrict__ RHb,
    const float* __restrict__ RTw, const float* __restrict__ RTb,
    unsigned short* __restrict__ h_bf) {
  const int b = blockIdx.x;
  const int tid = threadIdx.x;
  const int g = tid >> 8;
  const int m = (tid >> 1) & 127;
  const int hf = tid & 1;
  const float* W = g ? RTw : RHw;
  const float* Bb = g ? RTb : RHb;
  const float* XP = g ? xpt : xph;
  float wreg[3][64];
#pragma unroll
  for (int l = 0; l < 3; ++l)
#pragma unroll
    for (int j = 0; j < 64; ++j)
      wreg[l][j] = W[(size_t)(l * 128 + hf * 64 + j) * 128 + m];
  float bias[3];
#pragma unroll
  for (int l = 0; l < 3; ++l) bias[l] = Bb[l * 128 + m];

  __shared__ float s_lds[128];
  __shared__ float hg[128];
  __shared__ float tg[128];
  if (tid < 128) s_lds[tid] = 0.f;
  __syncthreads();

  for (int t = 0; t < 256; ++t) {
    const float xp = XP[(size_t)((b << 8) + t) * 128 + m];
#pragma unroll
    for (int l = 0; l < 3; ++l) {
      float acc = (hf == 0) ? (bias[l] + (l == 0 ? xp : 0.f)) : 0.f;
      const float* sp = s_lds + hf * 64;
#pragma unroll
      for (int j = 0; j < 64; ++j) acc += sp[j] * wreg[l][j];
      float tot = acc + __shfl_xor(acc, 1);
      if (hf == 0) {
        if (g == 0) hg[m] = tanh_fast(tot);
        else        tg[m] = sigmoid_fast(tot);
      }
      __syncthreads();
      if (tid < 128) {
        float tv = tg[tid];
        float sn = hg[tid] * tv + (1.f - tv) * s_lds[tid];
        s_lds[tid] = sn;
        h_bf[((size_t)(b * 3 + l) * 256 + t) * 128 + tid] = f2bf(sn);
      }
      __syncthreads();
    }
  }
}

// Uh2 = bf16(SCALE2LOG2E*(h.Uk_w[r]+Uk_b[r])) fused with hv = h.Vt_w[r],
// hv2 = h.V_w[r] (reuses the staged hl tile; 8-lane shuffle reduce per row).
__global__ __launch_bounds__(256, 2) void k_uh(
    const unsigned short* __restrict__ h_bf, const float* __restrict__ Uk_w,
    const float* __restrict__ Uk_b, const float* __restrict__ Vt_w,
    const float* __restrict__ V_w, unsigned short* __restrict__ Uh_bf,
    float* __restrict__ hv, float* __restrict__ hv2) {
  __shared__ float wl[128 * 128];  // 64 KB
  __shared__ float hl[32 * 128];   // 16 KB
  __shared__ float vtl[128], vwl[128];
  const int blk = blockIdx.x;      // 768 = 256 b x 3 r
  const int b = blk / 3, r = blk % 3;
  const int tid = threadIdx.x;
  for (int i = tid; i < 16384; i += 256) wl[i] = Uk_w[(size_t)r * 16384 + i];
  if (tid < 128) {
    vtl[tid] = Vt_w[r * 128 + tid];
    vwl[tid] = V_w[r * 128 + tid];
  }
  const int m = tid & 127, tr = tid >> 7;
  const float ub = Uk_b[r * 128 + m];
  const int hrow = tid >> 3, hc = tid & 7;
  for (int tt = 0; tt < 8; ++tt) {
    const size_t hbase = ((size_t)(b * 3 + r) * 256 + tt * 32) * 128;
    __syncthreads();
    const ushort8* hvv = (const ushort8*)(h_bf + hbase);
    for (int i = tid; i < 512; i += 256) {
      ushort8 u = hvv[i];
#pragma unroll
      for (int j = 0; j < 8; ++j) hl[i * 8 + j] = bf2f(u[j]);
    }
    __syncthreads();
    {
      float a1 = 0.f, a2 = 0.f;
      const float* hp = hl + hrow * 128 + hc * 16;
      const float* vt = vtl + hc * 16;
      const float* vw = vwl + hc * 16;
#pragma unroll
      for (int k = 0; k < 16; ++k) {
        float h = hp[k];
        a1 += h * vt[k];
        a2 += h * vw[k];
      }
      a1 += __shfl_xor(a1, 1); a1 += __shfl_xor(a1, 2); a1 += __shfl_xor(a1, 4);
      a2 += __shfl_xor(a2, 1); a2 += __shfl_xor(a2, 2); a2 += __shfl_xor(a2, 4);
      if (hc == 0) {
        size_t o = (size_t)(b * 3 + r) * 256 + tt * 32 + hrow;
        hv[o] = a1;
        hv2[o] = a2;
      }
    }
    for (int j = 0; j < 16; ++j) {
      int tl = tr * 16 + j;
      float acc = ub;
#pragma unroll 16
      for (int n = 0; n < 128; ++n) acc += hl[tl * 128 + n] * wl[n * 128 + m];
      Uh_bf[hbase + (size_t)tl * 128 + m] = f2bf(acc * SCALE2LOG2E);
    }
  }
}

// ---------------- attentive RHN decoder: one block per batch row -----------
// FINAL = round-8/13 proven-resident template: 48 persistent prescaled-Uh
// dwords/thread, 9-barrier schedule, cpart cell. FETCH ~31 MB, ~3.9 ms.
__global__ __launch_bounds__(1024, 4) void k_decoder(
    const float* __restrict__ y, const unsigned short* __restrict__ Uh_bf,
    const float* __restrict__ hv_g, const float* __restrict__ hv2_g,
    const float* __restrict__ Tk_w, const float* __restrict__ vk_w,
    const float* __restrict__ vk_b, const float* __restrict__ Wt_w,
    const float* __restrict__ Vt_b, const float* __restrict__ WHd,
    const float* __restrict__ WTd, const uint32* __restrict__ cellw,
    const float* __restrict__ RHb, const float* __restrict__ RTb,
    const float* __restrict__ W_w, const float* __restrict__ W_b,
    const float* __restrict__ V_b, float* __restrict__ out) {
  const int b = blockIdx.x, tid = threadIdx.x;

  __shared__ uint32 tk_lds[24576];  // 96 KiB packed prescaled bf16 n-pairs
  __shared__ __align__(8) float Ts_lds[3 * 136];  // padded 34-float windows
  __shared__ __align__(8) float vk_pad[3 * 136];  // -2*vk, same layout
  __shared__ __align__(8) float a_lds[768];
  __shared__ float hv_lds[768], hv2_lds[768];
  __shared__ __align__(8) float s_lds[128];
  __shared__ float cpart[8 * 128];
  __shared__ float bias_lds[1024];  // RHb[384] RTb[384] WHd[128] WTd[128]
  __shared__ float y_lds[256];
  __shared__ float redN[12], redD[12], redN2[12];
  __shared__ float svk_lds[3];
  __shared__ float ytil_lds;

  // ---- one-time LDS fills ----
  for (int i = tid; i < 24576; i += 1024) {
    int r = i >> 13, rem = i & 8191, j = rem >> 7, m = rem & 127;
    float g0 = Tk_w[(size_t)r * 16384 + (2 * j) * 128 + m] * SCALE2LOG2E;
    float g1 = Tk_w[(size_t)r * 16384 + (2 * j + 1) * 128 + m] * SCALE2LOG2E;
    tk_lds[r * 8192 + m * 64 + (j ^ (m & 31))] =
        (uint32)f2bf(g0) | ((uint32)f2bf(g1) << 16);
  }
  if (tid < 384) {
    int r = tid >> 7, m = tid & 127;
    vk_pad[r * 136 + (m >> 5) * 34 + (m & 31)] = -2.f * vk_w[tid];
    bias_lds[tid] = RHb[tid];
    bias_lds[384 + tid] = RTb[tid];
  }
  if (tid < 3) {
    float sv = vk_b[tid];
    for (int m = 0; m < 128; ++m) sv += vk_w[tid * 128 + m];
    svk_lds[tid] = sv;
  }
  if (tid < 128) {
    bias_lds[768 + tid] = WHd[tid];
    bias_lds[896 + tid] = WTd[tid];
    s_lds[tid] = 0.f;
  }
  if (tid < 256) y_lds[tid] = y[(b << 8) + tid];
  if (tid < 768) {
    hv_lds[tid] = hv_g[(size_t)b * 768 + tid];
    hv2_lds[tid] = hv2_g[(size_t)b * 768 + tid];
  }
  const float wt0 = Wt_w[0], vtb0 = Vt_b[0];

  // ---- persistent prescaled Uh: 3 r x 16 dwords = 48 VGPR ----
  const int t_e4 = tid >> 2, q4 = tid & 3;
  uint32 ureg[3][16];
#pragma unroll
  for (int r = 0; r < 3; ++r) {
    const uint4* up = (const uint4*)(Uh_bf +
        ((size_t)(b * 3 + r) * 256 + t_e4) * 128 + q4 * 32);
#pragma unroll
    for (int q = 0; q < 4; ++q) {
      uint4 v = up[q];
      ureg[r][4 * q + 0] = v.x;
      ureg[r][4 * q + 1] = v.y;
      ureg[r][4 * q + 2] = v.z;
      ureg[r][4 * q + 3] = v.w;
    }
  }
  uint32 zr;
  asm volatile("s_mov_b32 %0, 0" : "=s"(zr));
#pragma unroll
  for (int r = 0; r < 3; ++r)
#pragma unroll
    for (int q = 0; q < 16; ++q) ureg[r][q] ^= zr;
  __syncthreads();

  const int lane = tid & 63, wv = tid >> 6;
  // Ts-phase roles (tid < 768)
  const int r3t = (tid >> 8) & 3, m2 = (tid >> 1) & 127, p2 = tid & 1;
  // cell roles: 2 gates x 4 n2-chunks x 128 m
  const int gc = tid >> 9, ch = (tid >> 7) & 3, mc = tid & 127;
  const uint32* Wc = cellw + gc * 24576 + mc;
  const int n2base = ch * 16;

  for (int step = 0; step < 256; ++step) {
    // ---- Ts2[r][m] = s @ Tk2[r] ----
    if (tid < 768) {
      const uint32* tkp = tk_lds + r3t * 8192 + m2 * 64;
      const int swz = m2 & 31;
      const float* sp = s_lds + p2 * 64;
      const int jb = p2 * 32;
      float acc = 0.f;
#pragma unroll 8
      for (int jj = 0; jj < 32; ++jj) {
        uint32 w = tkp[(jb + jj) ^ swz];
        float2 sv = *(const float2*)(sp + 2 * jj);
        acc += sv.x * bf2f_lo(w) + sv.y * bf2f_hi(w);
      }
      float tot = acc + __shfl_xor(acc, 1);
      if (p2 == 0) Ts_lds[r3t * 136 + (m2 >> 5) * 34 + (m2 & 31)] = tot;
    }
    __syncthreads();  // (1)
    // ---- e[r][t'] = svk + sum(-2vk * rcp(exp2(Uh2+Ts2)+1))  (Uh in regs) ----
    {
      float er[3];
#pragma unroll
      for (int r = 0; r < 3; ++r) {
        const float2* ts2 = (const float2*)(Ts_lds + r * 136 + q4 * 34);
        const float2* vk2 = (const float2*)(vk_pad + r * 136 + q4 * 34);
        float acc0 = 0.f, acc1 = 0.f;
#pragma unroll
        for (int j = 0; j < 16; ++j) {
          uint32 w = ureg[r][j];
          float2 t2 = ts2[j], v2 = vk2[j];
          float z0 = exp2_fast(bf2f_lo(w) + t2.x);
          float z1 = exp2_fast(bf2f_hi(w) + t2.y);
          acc0 += v2.x * rcp_fast(z0 + 1.f);
          acc1 += v2.y * rcp_fast(z1 + 1.f);
        }
        float a = acc0 + acc1;
        a += __shfl_xor(a, 1);
        a += __shfl_xor(a, 2);
        er[r] = a;
      }
      if (q4 == 0) {
#pragma unroll
        for (int r = 0; r < 3; ++r) a_lds[r * 256 + t_e4] = er[r] + svk_lds[r];
      }
    }
    __syncthreads();  // (2)
    // ---- p = exp(e); num/den partial sums per r (no max-sub needed) ----
    {
      float pn = 0.f, pd = 0.f, pn2 = 0.f;
      if (tid < 768) {
        float p = __expf(a_lds[tid]);
        pd = p;
        pn = p * hv_lds[tid];
        if (step == 255) pn2 = p * hv2_lds[tid];
      }
#pragma unroll
      for (int off = 32; off; off >>= 1) {
        pn += __shfl_xor(pn, off);
        pd += __shfl_xor(pd, off);
      }
      if (step == 255) {
#pragma unroll
        for (int off = 32; off; off >>= 1) pn2 += __shfl_xor(pn2, off);
        if (lane == 0 && wv < 12) redN2[wv] = pn2;
      }
      if (lane == 0 && wv < 12) {
        redN[wv] = pn;
        redD[wv] = pd;
      }
    }
    __syncthreads();  // (3)
    // ---- cell: 3 micro-steps; l=0 dot overlaps ytil scalar ----
    const float2* sp2 = (const float2*)s_lds;
#pragma unroll
    for (int l = 0; l < 3; ++l) {
      {
        float acc = 0.f;
        const uint32* wp = Wc + (size_t)(l * 64 + n2base) * 128;
#pragma unroll 8
        for (int n2 = 0; n2 < 16; ++n2) {
          uint32 w = wp[(size_t)n2 * 128];
          float2 sv = sp2[n2base + n2];
          acc += sv.x * bf2f_lo(w) + sv.y * bf2f_hi(w);
        }
        cpart[(gc * 4 + ch) * 128 + mc] = acc;
        if (l == 0 && tid == 0) {
          float yt = y_lds[step] * wt0 + vtb0;
#pragma unroll
          for (int r = 0; r < 3; ++r) {
            float ns = redN[4 * r] + redN[4 * r + 1] + redN[4 * r + 2] + redN[4 * r + 3];
            float ds = redD[4 * r] + redD[4 * r + 1] + redD[4 * r + 2] + redD[4 * r + 3];
            yt += ns * rcp_fast(ds);
          }
          ytil_lds = yt;
        }
      }
      __syncthreads();  // cell A
      if (tid < 128) {
        float ha = cpart[tid] + cpart[128 + tid] + cpart[256 + tid] +
                   cpart[384 + tid] + bias_lds[l * 128 + tid];
        float ta = cpart[512 + tid] + cpart[640 + tid] + cpart[768 + tid] +
                   cpart[896 + tid] + bias_lds[384 + l * 128 + tid];
        if (l == 0) {
          float yt = ytil_lds;
          ha += yt * bias_lds[768 + tid];
          ta += yt * bias_lds[896 + tid];
        }
        float hvv = tanh_fast(ha);
        float tv = sigmoid_fast(ta);
        s_lds[tid] = hvv * tv + (1.f - tv) * s_lds[tid];
      }
      __syncthreads();  // cell B
    }
  }
  // ---- output head: out[b] = s.W_w + W_b + V_b + sum_r num2[r]/den[r] ----
  if (tid < 64) {
    float acc = s_lds[tid] * W_w[tid] + s_lds[tid + 64] * W_w[tid + 64];
#pragma unroll
    for (int off = 32; off; off >>= 1) acc += __shfl_xor(acc, off);
    if (tid == 0) {
      float o = acc + W_b[0] + V_b[0];
#pragma unroll
      for (int r = 0; r < 3; ++r) {
        float ns = redN2[4 * r] + redN2[4 * r + 1] + redN2[4 * r + 2] + redN2[4 * r + 3];
        float ds = redD[4 * r] + redD[4 * r + 1] + redD[4 * r + 2] + redD[4 * r + 3];
        o += ns * rcp_fast(ds);
      }
      out[b] = o;
    }
  }
}

extern "C" void kernel_launch(void* const* d_in, const int* in_sizes, int n_in,
                              void* d_out, int out_size, void* d_ws,
                              size_t ws_size, hipStream_t stream) {
  (void)in_sizes; (void)n_in; (void)out_size; (void)ws_size;
  const float* x    = (const float*)d_in[0];
  const float* y    = (const float*)d_in[1];
  const float* c0w  = (const float*)d_in[2];
  const float* c0b  = (const float*)d_in[3];
  const float* c1w  = (const float*)d_in[4];
  const float* c1b  = (const float*)d_in[5];
  const float* c2ew = (const float*)d_in[6];
  const float* c2eb = (const float*)d_in[7];
  const float* eWH  = (const float*)d_in[8];
  const float* eWT  = (const float*)d_in[9];
  const float* eRHw = (const float*)d_in[10];
  const float* eRHb = (const float*)d_in[11];
  const float* eRTw = (const float*)d_in[12];
  const float* eRTb = (const float*)d_in[13];
  const float* dWH  = (const float*)d_in[14];
  const float* dWT  = (const float*)d_in[15];
  const float* dRHw = (const float*)d_in[16];
  const float* dRHb = (const float*)d_in[17];
  const float* dRTw = (const float*)d_in[18];
  const float* dRTb = (const float*)d_in[19];
  const float* Tk   = (const float*)d_in[20];
  const float* Ukw  = (const float*)d_in[21];
  const float* Ukb  = (const float*)d_in[22];
  const float* vkw  = (const float*)d_in[23];
  const float* vkb  = (const float*)d_in[24];
  const float* Wtw  = (const float*)d_in[25];
  const float* Vtw  = (const float*)d_in[26];
  const float* Vtb  = (const float*)d_in[27];
  const float* Ww   = (const float*)d_in[28];
  const float* Wb   = (const float*)d_in[29];
  const float* Vw   = (const float*)d_in[30];
  const float* Vb   = (const float*)d_in[31];
  float* out = (float*)d_out;
  float* ws = (float*)d_ws;

  // Workspace layout (float units), same as round 5.
  unsigned short* h_bf  = (unsigned short*)ws;
  unsigned short* Uh_bf = (unsigned short*)(ws + 12582912);
  float* xph = ws + 12582912;
  float* xpt = ws + 20971520;
  float* c0o = ws + 29360128;
  float* hv  = ws + 29360128;   // aliases c0o (dead by k_uh time)
  float* hv2 = ws + 30146560;
  float* c1o = ws + 33554432;
  uint32* cellw = (uint32*)(ws + 37748736);

  k_prep<<<192, 256, 0, stream>>>(dRHw, dRTw, cellw);
  k_conv0<<<1024, 256, 0, stream>>>(x, c0w, c0b, c0o);
  k_conv1<<<2048, 256, 0, stream>>>(c0o, c1w, c1b, c1o);
  k_c2e_proj<<<1024, 256, 0, stream>>>(c1o, c2ew, c2eb, eWH, eWT, xph, xpt);
  k_encoder<<<256, 512, 0, stream>>>(xph, xpt, eRHw, eRHb, eRTw, eRTb, h_bf);
  k_uh<<<768, 256, 0, stream>>>(h_bf, Ukw, Ukb, Vtw, Vw, Uh_bf, hv, hv2);
  k_decoder<<<256, 1024, 0, stream>>>(y, Uh_bf, hv, hv2, Tk, vkw, vkb, Wtw,
                                      Vtb, dWH, dWT, cellw, dRHb, dRTb,
                                      Ww, Wb, Vb, out);
}